// Round 1
// baseline (56.437 us; speedup 1.0000x reference)
//
#include <hip/hip_runtime.h>

namespace {
constexpr int   kCells  = 512 * 28 * 28;   // 401408
constexpr int   kPairs  = kCells / 2;      // 200704
constexpr float kLCoord = 5.0f;
constexpr float kLNoobj = 0.5f;
constexpr float kInvS   = 1.0f / 28.0f;
constexpr float kInvN   = 1.0f / 512.0f;
}

// p, t point at one cell's 30 floats each.
__device__ __forceinline__ float cell_loss(const float* __restrict__ p,
                                           const float* __restrict__ t) {
    const float coo = (t[4] > 0.0f) ? 1.0f : 0.0f;

    // target box 0 -> xyxy
    const float t_cx = t[0] * kInvS, t_cy = t[1] * kInvS;
    const float t_ltx = t_cx - 0.5f * t[2];
    const float t_lty = t_cy - 0.5f * t[3];
    const float t_rbx = t_cx + 0.5f * t[2];
    const float t_rby = t_cy + 0.5f * t[3];
    const float area2 = (t_rbx - t_ltx) * (t_rby - t_lty);

    float iou0, iou1;
    #pragma unroll
    for (int b = 0; b < 2; ++b) {
        const float* pb = p + 5 * b;
        const float p_cx = pb[0] * kInvS, p_cy = pb[1] * kInvS;
        const float p_ltx = p_cx - 0.5f * pb[2];
        const float p_lty = p_cy - 0.5f * pb[3];
        const float p_rbx = p_cx + 0.5f * pb[2];
        const float p_rby = p_cy + 0.5f * pb[3];
        const float ltx = fmaxf(p_ltx, t_ltx);
        const float lty = fmaxf(p_lty, t_lty);
        const float rbx = fminf(p_rbx, t_rbx);
        const float rby = fminf(p_rby, t_rby);
        const float w = fmaxf(rbx - ltx, 0.0f);
        const float h = fmaxf(rby - lty, 0.0f);
        const float inter = w * h;
        const float area1 = (p_rbx - p_ltx) * (p_rby - p_lty);
        const float iou = inter / (area1 + area2 - inter);
        if (b == 0) iou0 = iou; else iou1 = iou;
    }
    // jnp.argmax picks the FIRST max on ties -> idx 1 only if strictly greater.
    const int   max_idx = (iou1 > iou0) ? 1 : 0;
    const float max_iou = fmaxf(iou0, iou1);

    float loc = 0.0f, contain = 0.0f, notresp = 0.0f, nooobj = 0.0f;
    #pragma unroll
    for (int b = 0; b < 2; ++b) {
        const float* pb = p + 5 * b;
        const float* tb = t + 5 * b;
        const float dx = pb[0] - tb[0];
        const float dy = pb[1] - tb[1];
        const float d_xy = dx * dx + dy * dy;
        const float sw = sqrtf(pb[2]) - sqrtf(tb[2]);
        const float sh = sqrtf(pb[3]) - sqrtf(tb[3]);
        const float d_wh = sw * sw + sh * sh;
        const float resp   = (b == max_idx) ? 1.0f : 0.0f;
        const float w_resp = coo * resp;
        const float w_not  = coo * (1.0f - resp);
        loc += w_resp * (d_xy + d_wh);
        const float dc = pb[4] - max_iou;
        contain += w_resp * dc * dc;
        notresp += w_not * pb[4] * pb[4];
        const float dn = pb[4] - tb[4];
        nooobj += (1.0f - coo) * dn * dn;
    }

    float cls = 0.0f;
    #pragma unroll
    for (int j = 10; j < 30; ++j) {
        const float d = p[j] - t[j];
        cls += d * d;
    }
    cls *= coo;

    return kLCoord * loc + contain + kLNoobj * (notresp + nooobj) + cls;
}

__global__ void zero_out_kernel(float* __restrict__ out) {
    if (threadIdx.x == 0 && blockIdx.x == 0) out[0] = 0.0f;
}

__global__ __launch_bounds__(256) void yolo_loss_kernel(
        const float* __restrict__ pred,
        const float* __restrict__ targ,
        float* __restrict__ out) {
    const int pair = blockIdx.x * blockDim.x + threadIdx.x;

    float local = 0.0f;
    if (pair < kPairs) {
        // A pair of cells = 60 floats = 240 bytes, 16B-aligned -> float4 loads.
        float pbuf[60], tbuf[60];
        const float4* p4 = reinterpret_cast<const float4*>(pred + (size_t)pair * 60);
        const float4* t4 = reinterpret_cast<const float4*>(targ + (size_t)pair * 60);
        float4* pb4 = reinterpret_cast<float4*>(pbuf);
        float4* tb4 = reinterpret_cast<float4*>(tbuf);
        #pragma unroll
        for (int i = 0; i < 15; ++i) {
            pb4[i] = p4[i];
            tb4[i] = t4[i];
        }
        local = cell_loss(pbuf, tbuf) + cell_loss(pbuf + 30, tbuf + 30);
    }

    // wave (64-lane) reduction
    #pragma unroll
    for (int off = 32; off > 0; off >>= 1)
        local += __shfl_down(local, off, 64);

    __shared__ float wsum[4];
    const int lane = threadIdx.x & 63;
    const int wid  = threadIdx.x >> 6;
    if (lane == 0) wsum[wid] = local;
    __syncthreads();
    if (threadIdx.x == 0) {
        const float s = wsum[0] + wsum[1] + wsum[2] + wsum[3];
        atomicAdd(out, s * kInvN);
    }
}

extern "C" void kernel_launch(void* const* d_in, const int* in_sizes, int n_in,
                              void* d_out, int out_size, void* d_ws, size_t ws_size,
                              hipStream_t stream) {
    const float* pred = (const float*)d_in[0];
    const float* targ = (const float*)d_in[1];
    float* out = (float*)d_out;

    zero_out_kernel<<<1, 64, 0, stream>>>(out);

    const int threads = 256;
    const int blocks  = (kPairs + threads - 1) / threads;  // 784
    yolo_loss_kernel<<<blocks, threads, 0, stream>>>(pred, targ, out);
}

// Round 2
// 23.044 us; speedup vs baseline: 2.4491x; 2.4491x over previous
//
#include <hip/hip_runtime.h>

namespace {
constexpr int   kS          = 28;
constexpr int   kBatch      = 512;
constexpr int   kCells      = kBatch * kS * kS;      // 401408
constexpr int   kTPB        = 256;
constexpr int   kTileCells  = 256;                   // one cell per thread
constexpr int   kTileF      = kTileCells * 30;       // 7680 floats per tensor tile
constexpr int   kNBlocks    = kCells / kTileCells;   // 1568 (exact)
constexpr int   kChunks     = kTileF / (64 * 4);     // 30 chunks of 64 lanes x float4
constexpr float kLCoord     = 5.0f;
constexpr float kLNoobj     = 0.5f;
constexpr float kInvS       = 1.0f / 28.0f;
constexpr float kInvN       = 1.0f / 512.0f;
}

__device__ __forceinline__ void async16(const float* g, float* l) {
    __builtin_amdgcn_global_load_lds(
        (const __attribute__((address_space(1))) void*)g,
        (__attribute__((address_space(3))) void*)l,
        16, 0, 0);
}

// p, t point at one cell's 30 floats (in LDS).
__device__ __forceinline__ float cell_loss(const float* p, const float* t) {
    const float coo = (t[4] > 0.0f) ? 1.0f : 0.0f;

    const float t_cx = t[0] * kInvS, t_cy = t[1] * kInvS;
    const float t_ltx = t_cx - 0.5f * t[2];
    const float t_lty = t_cy - 0.5f * t[3];
    const float t_rbx = t_cx + 0.5f * t[2];
    const float t_rby = t_cy + 0.5f * t[3];
    const float area2 = (t_rbx - t_ltx) * (t_rby - t_lty);

    float iou0 = 0.0f, iou1 = 0.0f;
    #pragma unroll
    for (int b = 0; b < 2; ++b) {
        const float* pb = p + 5 * b;
        const float p_cx = pb[0] * kInvS, p_cy = pb[1] * kInvS;
        const float p_ltx = p_cx - 0.5f * pb[2];
        const float p_lty = p_cy - 0.5f * pb[3];
        const float p_rbx = p_cx + 0.5f * pb[2];
        const float p_rby = p_cy + 0.5f * pb[3];
        const float ltx = fmaxf(p_ltx, t_ltx);
        const float lty = fmaxf(p_lty, t_lty);
        const float rbx = fminf(p_rbx, t_rbx);
        const float rby = fminf(p_rby, t_rby);
        const float w = fmaxf(rbx - ltx, 0.0f);
        const float h = fmaxf(rby - lty, 0.0f);
        const float inter = w * h;
        const float area1 = (p_rbx - p_ltx) * (p_rby - p_lty);
        const float iou = inter / (area1 + area2 - inter);
        if (b == 0) iou0 = iou; else iou1 = iou;
    }
    // jnp.argmax picks the FIRST max on ties -> idx 1 only if strictly greater.
    const int   max_idx = (iou1 > iou0) ? 1 : 0;
    const float max_iou = fmaxf(iou0, iou1);

    float loc = 0.0f, contain = 0.0f, notresp = 0.0f, nooobj = 0.0f;
    #pragma unroll
    for (int b = 0; b < 2; ++b) {
        const float* pb = p + 5 * b;
        const float* tb = t + 5 * b;
        const float dx = pb[0] - tb[0];
        const float dy = pb[1] - tb[1];
        const float d_xy = dx * dx + dy * dy;
        const float sw = sqrtf(pb[2]) - sqrtf(tb[2]);
        const float sh = sqrtf(pb[3]) - sqrtf(tb[3]);
        const float d_wh = sw * sw + sh * sh;
        const float resp   = (b == max_idx) ? 1.0f : 0.0f;
        const float w_resp = coo * resp;
        const float w_not  = coo * (1.0f - resp);
        loc += w_resp * (d_xy + d_wh);
        const float dc = pb[4] - max_iou;
        contain += w_resp * dc * dc;
        notresp += w_not * pb[4] * pb[4];
        const float dn = pb[4] - tb[4];
        nooobj += (1.0f - coo) * dn * dn;
    }

    float cls = 0.0f;
    #pragma unroll
    for (int j = 10; j < 30; ++j) {
        const float d = p[j] - t[j];
        cls += d * d;
    }
    cls *= coo;

    return kLCoord * loc + contain + kLNoobj * (notresp + nooobj) + cls;
}

template <bool USE_WS>
__global__ __launch_bounds__(kTPB) void yolo_loss_kernel(
        const float* __restrict__ pred,
        const float* __restrict__ targ,
        float* __restrict__ dst) {
    __shared__ float lp[kTileF];
    __shared__ float lt[kTileF];
    __shared__ float wsum[kTPB / 64];

    const int tid  = threadIdx.x;
    const int lane = tid & 63;
    const int wid  = tid >> 6;

    const float* gp = pred + (size_t)blockIdx.x * kTileF;
    const float* gt = targ + (size_t)blockIdx.x * kTileF;

    // Coalesced async global->LDS staging: chunk c = 64 lanes x 16B = 1024B.
    for (int c = wid; c < kChunks; c += kTPB / 64) {
        const int f = c * 256 + lane * 4;   // float index of this lane's 16B
        async16(gp + f, &lp[c * 256]);
        async16(gt + f, &lt[c * 256]);
    }
    __syncthreads();   // drains vmcnt + barrier

    float local = cell_loss(&lp[tid * 30], &lt[tid * 30]);

    #pragma unroll
    for (int off = 32; off > 0; off >>= 1)
        local += __shfl_down(local, off, 64);

    if (lane == 0) wsum[wid] = local;
    __syncthreads();
    if (tid == 0) {
        const float s = wsum[0] + wsum[1] + wsum[2] + wsum[3];
        if (USE_WS) dst[blockIdx.x] = s;
        else        atomicAdd(dst, s * kInvN);
    }
}

__global__ __launch_bounds__(256) void reduce_kernel(
        const float* __restrict__ part, float* __restrict__ out) {
    __shared__ float wsum[4];
    float s = 0.0f;
    for (int i = threadIdx.x; i < kNBlocks; i += 256) s += part[i];
    #pragma unroll
    for (int off = 32; off > 0; off >>= 1)
        s += __shfl_down(s, off, 64);
    const int lane = threadIdx.x & 63;
    const int wid  = threadIdx.x >> 6;
    if (lane == 0) wsum[wid] = s;
    __syncthreads();
    if (threadIdx.x == 0)
        out[0] = (wsum[0] + wsum[1] + wsum[2] + wsum[3]) * kInvN;
}

__global__ void zero_out_kernel(float* __restrict__ out) {
    if (threadIdx.x == 0) out[0] = 0.0f;
}

extern "C" void kernel_launch(void* const* d_in, const int* in_sizes, int n_in,
                              void* d_out, int out_size, void* d_ws, size_t ws_size,
                              hipStream_t stream) {
    const float* pred = (const float*)d_in[0];
    const float* targ = (const float*)d_in[1];
    float* out = (float*)d_out;

    if (ws_size >= (size_t)kNBlocks * sizeof(float)) {
        float* part = (float*)d_ws;
        yolo_loss_kernel<true><<<kNBlocks, kTPB, 0, stream>>>(pred, targ, part);
        reduce_kernel<<<1, 256, 0, stream>>>(part, out);
    } else {
        zero_out_kernel<<<1, 64, 0, stream>>>(out);
        yolo_loss_kernel<false><<<kNBlocks, kTPB, 0, stream>>>(pred, targ, out);
    }
}